// Round 5
// baseline (754.278 us; speedup 1.0000x reference)
//
#include <hip/hip_runtime.h>
#include <stdint.h>
#include <stddef.h>

// ---------------------------------------------------------------------------
// InverseImportanceLinear: out = x @ W_deq^T + bias
//   W_deq[k,n] = (Q[k,n] - zeros[k,n/64]) * scales[k,n/64] * mu2[k] * mu1[n]
// Phase 1: dequant W -> bf16 workspace (fixed-column threads, mu1 in regs),
//          convert x -> bf16 workspace.
// Phase 2: 256x256-tile bf16 MFMA GEMM using 32x32x16 MFMA, 2 phases/K-tile
// (4 barriers/K-tile), even 4-slot staging, counted vmcnt(2) gates, T2
// swizzle, T5 setprio, T1 XCD swizzle. Each LDS fragment read exactly once.
// ---------------------------------------------------------------------------

typedef __attribute__((ext_vector_type(8)))  short bfrag;   // 8 bf16 = 4 VGPRs
typedef __attribute__((ext_vector_type(4)))  short s16x4;   // 4 bf16 = 8 B
typedef __attribute__((ext_vector_type(4)))  float f32x4;
typedef __attribute__((ext_vector_type(16))) float f32x16;  // 32x32 acc
typedef __attribute__((ext_vector_type(4)))  int   i32x4;

__device__ __forceinline__ short f2bf(float f) {
    uint32_t u = __float_as_uint(f);
    u += 0x7fffu + ((u >> 16) & 1u);        // round-to-nearest-even
    return (short)(u >> 16);
}

__device__ __forceinline__ void gload_lds16(const void* g, void* l) {
    __builtin_amdgcn_global_load_lds(
        (const __attribute__((address_space(1))) void*)g,
        (__attribute__((address_space(3))) void*)l,
        16, 0, 0);
}

// ---- phase 1a: x fp32 -> bf16, 4 elems/thread, lane-stride 16B -----------
__global__ void cvt_x_kernel(const float* __restrict__ x, short* __restrict__ xb,
                             int total4) {
    for (int i = blockIdx.x * 256 + threadIdx.x; i < total4;
         i += gridDim.x * 256) {
        f32x4 a = ((const f32x4*)x)[i];
        s16x4 o;
        o[0] = f2bf(a[0]); o[1] = f2bf(a[1]);
        o[2] = f2bf(a[2]); o[3] = f2bf(a[3]);
        ((s16x4*)xb)[i] = o;
    }
}

// ---- phase 1b: dequant W -> bf16, fixed 4-column window per thread -------
// Block (bx,by): columns [bx*1024, +1024), rows [by*KR, +KR). mu1 and the
// group index are loop-invariant per thread; per row: 16B Q load + 8B store.
__global__ void deq_w_kernel(const int* __restrict__ Q,
                             const float* __restrict__ scales,
                             const float* __restrict__ zeros,
                             const float* __restrict__ mu1,
                             const float* __restrict__ mu2,
                             short* __restrict__ wb,
                             int k0, int rows, int N, int NG) {
    const int n0 = blockIdx.x * 1024 + threadIdx.x * 4;
    const int g  = n0 >> 6;                  // GROUP_SIZE = 64
    const int KR = rows >> 7;                // gridDim.y == 128, rows % 128 == 0
    const int kb = blockIdx.y * KR;
    const f32x4 u = *(const f32x4*)(mu1 + n0);
    for (int k = kb; k < kb + KR; ++k) {
        const int kg = k0 + k;
        const float s = scales[(size_t)kg * NG + g] * mu2[kg];
        const float z = zeros[(size_t)kg * NG + g];
        i32x4 q = *(const i32x4*)(Q + (size_t)kg * N + n0);
        s16x4 o;
        o[0] = f2bf(((float)q[0] - z) * s * u[0]);
        o[1] = f2bf(((float)q[1] - z) * s * u[1]);
        o[2] = f2bf(((float)q[2] - z) * s * u[2]);
        o[3] = f2bf(((float)q[3] - z) * s * u[3]);
        *(s16x4*)(wb + (size_t)k * N + n0) = o;
    }
}

// ---- phase 2: 256x256 GEMM via mfma_f32_32x32x16_bf16 --------------------
// A: M x Kc bf16 row-major (x). B: rows x Kc bf16 row-major (W chunk).
// 512 threads = 8 waves (2M x 4N); per-wave 128x64 output; BK=64.
// LDS 128 KiB: buf{0,1} x { A 32 KiB | B 32 KiB }, 16B-granule XOR swizzle
// (read granule ^= row&7; inverse folded into global src; dest linear).
// Per K-tile: 2 phases (MQ half): P0 reads A-half(8)+B(8), P1 reads A-half(8);
// B frags held across both. 24 ds_read_b128 / wave / K-tile, 4 barriers.

__global__ __launch_bounds__(512, 2)
void gemm8p_kernel(const short* __restrict__ A, const short* __restrict__ B,
                   const float* __restrict__ bias, float* __restrict__ C,
                   int Kc, int Nout, int col0, int GX) {
    extern __shared__ __attribute__((aligned(16))) char smem[];   // 131072 B

    const int tid   = threadIdx.x;
    const int lane  = tid & 63;
    const int wid   = tid >> 6;
    const int wm    = wid >> 2;             // 0..1
    const int wn    = wid & 3;              // 0..3
    const int l31   = lane & 31;
    const int hib   = (lane >> 5) << 4;     // k-half byte offset (0 or 16)
    const int sw    = (lane & 7) << 4;      // read-side XOR swizzle (row&7==lane&7)

    // XCD-aware bijective swizzle (grid size is GX*16, multiple of 8)
    const int nwg = (int)gridDim.x;
    const int cpx = nwg >> 3;
    const int bid = (int)blockIdx.x;
    const int swz = (bid & 7) * cpx + (bid >> 3);
    const int bx  = swz % GX;               // over B rows (C cols)
    const int by  = swz / GX;               // over A rows
    const int bm  = by * 256;
    const int bnl = bx * 256;

    const int KB = Kc * 2;                  // row stride in bytes
    // staging: thread covers row (tid>>3), 16B granule (tid&7); inverse
    // swizzle folded into the global column; LDS dest linear.
    const int swcol = ((tid ^ (tid >> 3)) & 7) << 4;
    const char* srcA = (const char*)A + (size_t)(bm  + (tid >> 3)) * KB + swcol;
    const char* srcB = (const char*)B + (size_t)(bnl + (tid >> 3)) * KB + swcol;

    f32x16 acc[4][2];
#pragma unroll
    for (int i = 0; i < 4; i++)
#pragma unroll
        for (int j = 0; j < 2; j++)
#pragma unroll
            for (int e = 0; e < 16; e++)
                acc[i][j][e] = 0.f;

    const int NT = Kc / 64;                 // K-tiles (even; Kc % 128 == 0)

#define STG_A(t, q) gload_lds16(srcA + (size_t)(t) * 128 + (size_t)(q) * 64 * KB, \
                                smem + ((t) & 1) * 65536 + (q) * 8192 + (tid << 4))
#define STG_B(t, q) gload_lds16(srcB + (size_t)(t) * 128 + (size_t)(q) * 64 * KB, \
                                smem + ((t) & 1) * 65536 + 32768 + (q) * 8192 + (tid << 4))
#define LDF(base, row, ks) (*(const bfrag*)((base) + (size_t)(row) * 128 + ((((ks) << 5) + hib) ^ sw)))
#define MM(I, J, AF, BF) acc[I][J] = __builtin_amdgcn_mfma_f32_32x32x16_bf16(AF, BF, acc[I][J], 0, 0, 0)

// read one A half (2 row-positions x 4 k-steps = 8 frags)
#define RD_A(Ab_, MQ) do { const int ra_ = wm * 128 + (MQ) * 64 + l31;          \
    Af[0] = LDF(Ab_, ra_,      0); Af[1] = LDF(Ab_, ra_,      1);               \
    Af[2] = LDF(Ab_, ra_,      2); Af[3] = LDF(Ab_, ra_,      3);               \
    Af[4] = LDF(Ab_, ra_ + 32, 0); Af[5] = LDF(Ab_, ra_ + 32, 1);               \
    Af[6] = LDF(Ab_, ra_ + 32, 2); Af[7] = LDF(Ab_, ra_ + 32, 3); } while (0)

// read B (2 col-positions x 4 k-steps = 8 frags), held across both MQ phases
#define RD_B(Bb_) do { const int rb_ = wn * 64 + l31;                           \
    Bf[0] = LDF(Bb_, rb_,      0); Bf[1] = LDF(Bb_, rb_,      1);               \
    Bf[2] = LDF(Bb_, rb_,      2); Bf[3] = LDF(Bb_, rb_,      3);               \
    Bf[4] = LDF(Bb_, rb_ + 32, 0); Bf[5] = LDF(Bb_, rb_ + 32, 1);               \
    Bf[6] = LDF(Bb_, rb_ + 32, 2); Bf[7] = LDF(Bb_, rb_ + 32, 3); } while (0)

// barrier, wait LDS, 16 MFMA for one M-half (4 acc chains of depth 4)
#define QUAD(MQ) do {                                                           \
    __builtin_amdgcn_s_barrier();                                               \
    asm volatile("s_waitcnt lgkmcnt(0)" ::: "memory");                          \
    __builtin_amdgcn_s_setprio(1);                                              \
    MM((MQ)*2 + 0, 0, Af[0], Bf[0]); MM((MQ)*2 + 0, 1, Af[0], Bf[4]);           \
    MM((MQ)*2 + 1, 0, Af[4], Bf[0]); MM((MQ)*2 + 1, 1, Af[4], Bf[4]);           \
    MM((MQ)*2 + 0, 0, Af[1], Bf[1]); MM((MQ)*2 + 0, 1, Af[1], Bf[5]);           \
    MM((MQ)*2 + 1, 0, Af[5], Bf[1]); MM((MQ)*2 + 1, 1, Af[5], Bf[5]);           \
    MM((MQ)*2 + 0, 0, Af[2], Bf[2]); MM((MQ)*2 + 0, 1, Af[2], Bf[6]);           \
    MM((MQ)*2 + 1, 0, Af[6], Bf[2]); MM((MQ)*2 + 1, 1, Af[6], Bf[6]);           \
    MM((MQ)*2 + 0, 0, Af[3], Bf[3]); MM((MQ)*2 + 0, 1, Af[3], Bf[7]);           \
    MM((MQ)*2 + 1, 0, Af[7], Bf[3]); MM((MQ)*2 + 1, 1, Af[7], Bf[7]);           \
    __builtin_amdgcn_s_setprio(0);                                              \
} while (0)

    // prologue: tile0 fully + tile1 quarters A0,A2; gate leaves 2 in flight.
    STG_A(0, 0); STG_A(0, 1); STG_A(0, 2); STG_A(0, 3);
    STG_B(0, 0); STG_B(0, 1); STG_B(0, 2); STG_B(0, 3);
    STG_A(1, 0); STG_A(1, 2);
    asm volatile("s_waitcnt vmcnt(2)" ::: "memory");
    __builtin_amdgcn_s_barrier();

    bfrag Af[8], Bf[8];

    // Stage-slot schedule (4 slots/phase, carry = {A0,A2} of next odd tile).
    // Gate arithmetic (per thread): at P2-end outstanding = carry2 + 4 + 4
    // = 10 -> vmcnt(2) completes all 8 of tile tb, leaves tc.A0,A2. Same at
    // P4-end for tc/td. Overwrite safety: every staged quarter is >=1
    // barrier after its region's reads were drained by that phase's lgkm(0);
    // same-phase stages touch only quarters disjoint from that phase's reads
    // (P2/P4 read A-quarters {1,3}, stage {0,2}).
    for (int it = 0; it < NT / 2; ++it) {
        const int tb = 2 * it + 1;
        int tc = 2 * it + 2; if (tc > NT - 1) tc = NT - 1;   // clamp: idempotent
        int td = 2 * it + 3; if (td > NT - 1) td = NT - 1;   // same-data rewrite
        const char* Ab0 = smem;
        const char* Bb0 = smem + 32768;
        const char* Ab1 = smem + 65536;
        const char* Bb1 = smem + 98304;

        // P1: tile-even MQ0 (reads A-half0 + all B of buf0)
        RD_A(Ab0, 0); RD_B(Bb0);
        STG_A(tb, 1); STG_A(tb, 3); STG_B(tb, 0); STG_B(tb, 1);
        QUAD(0);
        __builtin_amdgcn_s_barrier();

        // P2: tile-even MQ1
        RD_A(Ab0, 1);
        STG_B(tb, 2); STG_B(tb, 3); STG_A(tc, 0); STG_A(tc, 2);
        QUAD(1);
        asm volatile("s_waitcnt vmcnt(2)" ::: "memory");
        __builtin_amdgcn_s_barrier();

        // P3: tile-odd MQ0
        RD_A(Ab1, 0); RD_B(Bb1);
        STG_A(tc, 1); STG_A(tc, 3); STG_B(tc, 0); STG_B(tc, 1);
        QUAD(0);
        __builtin_amdgcn_s_barrier();

        // P4: tile-odd MQ1
        RD_A(Ab1, 1);
        STG_B(tc, 2); STG_B(tc, 3); STG_A(td, 0); STG_A(td, 2);
        QUAD(1);
        asm volatile("s_waitcnt vmcnt(2)" ::: "memory");
        __builtin_amdgcn_s_barrier();
    }

#undef QUAD
#undef RD_B
#undef RD_A
#undef MM
#undef LDF
#undef STG_B
#undef STG_A

    // epilogue: 32x32 C/D layout col = lane&31, row = (reg&3)+8*(reg>>2)+4*(lane>>5)
    const int rql = 4 * (lane >> 5);
#pragma unroll
    for (int j = 0; j < 2; ++j) {
        const int col = col0 + bnl + wn * 64 + j * 32 + l31;
        const float bv = bias[col];
#pragma unroll
        for (int i = 0; i < 4; ++i) {
            const int rowb = bm + wm * 128 + i * 32 + rql;
#pragma unroll
            for (int reg = 0; reg < 16; ++reg) {
                const int row = rowb + (reg & 3) + 8 * (reg >> 2);
                C[(size_t)row * Nout + col] = acc[i][j][reg] + bv;
            }
        }
    }
}

// ---- emergency fallback (workspace too small / shape mismatch) -----------
__global__ void naive_kernel(const float* __restrict__ x, const int* __restrict__ Q,
                             const float* __restrict__ scales, const float* __restrict__ zeros,
                             const float* __restrict__ mu1, const float* __restrict__ mu2,
                             const float* __restrict__ bias, float* __restrict__ out,
                             int T, int N, int K, int NG) {
    long long total = (long long)T * K;
    for (long long idx = blockIdx.x * 256ll + threadIdx.x; idx < total;
         idx += (long long)gridDim.x * 256ll) {
        int t = (int)(idx / K);
        int k = (int)(idx - (long long)t * K);
        float s = 0.f;
        for (int n = 0; n < N; n++) {
            int g = n >> 6;
            float w = ((float)Q[(size_t)k * N + n] - zeros[(size_t)k * NG + g]) *
                      scales[(size_t)k * NG + g];
            s += x[(size_t)t * N + n] * w * mu1[n];
        }
        out[idx] = s * mu2[k] + bias[k];
    }
}

extern "C" void kernel_launch(void* const* d_in, const int* in_sizes, int n_in,
                              void* d_out, int out_size, void* d_ws, size_t ws_size,
                              hipStream_t stream) {
    const float* x      = (const float*)d_in[0];
    const int*   Q      = (const int*)d_in[1];
    const float* scales = (const float*)d_in[2];
    const float* zeros  = (const float*)d_in[3];
    const float* mu1    = (const float*)d_in[4];
    const float* mu2    = (const float*)d_in[5];
    const float* bias   = (const float*)d_in[6];
    float* out = (float*)d_out;

    const int N  = in_sizes[4];            // 4096 (contraction)
    const int K  = in_sizes[5];            // 11264 (output cols)
    const int T  = in_sizes[0] / N;        // 4096 (output rows)
    const int NG = in_sizes[2] / K;        // 64 groups

    const size_t xb_bytes  = (size_t)T * N * 2;      // x in bf16
    const size_t row_bytes = (size_t)N * 2;          // one W row in bf16

    const bool shape_ok = (T % 256 == 0) && (K % 256 == 0) &&
                          (N % 1024 == 0) && (N % 128 == 0);

    if (!shape_ok || ws_size < xb_bytes + 256 * row_bytes) {
        naive_kernel<<<4096, 256, 0, stream>>>(x, Q, scales, zeros, mu1, mu2,
                                               bias, out, T, N, K, NG);
        return;
    }

    static bool attr_done = false;
    if (!attr_done) {
        (void)hipFuncSetAttribute(reinterpret_cast<const void*>(gemm8p_kernel),
                                  hipFuncAttributeMaxDynamicSharedMemorySize,
                                  131072);
        attr_done = true;
    }

    short* xb = (short*)d_ws;
    short* wb = (short*)((char*)d_ws + xb_bytes);
    size_t max_rows = (ws_size - xb_bytes) / row_bytes;
    int CH = (int)((max_rows / 256) * 256);
    if (CH > K) CH = K;

    cvt_x_kernel<<<2048, 256, 0, stream>>>(x, xb, T * (N / 4));

    for (int c0 = 0; c0 < K; c0 += CH) {
        int rows = (K - c0 < CH) ? (K - c0) : CH;
        // rows % 256 == 0 always -> rows % 128 == 0; grid (N/1024, 128)
        dim3 dgrid(N / 1024, 128);
        deq_w_kernel<<<dgrid, 256, 0, stream>>>(Q, scales, zeros, mu1, mu2, wb,
                                                c0, rows, N, NG);
        const int GX = rows / 256;
        dim3 ggrid(GX * (T / 256));
        gemm8p_kernel<<<ggrid, 512, 131072, stream>>>(xb, wb, bias, out,
                                                      N, K, c0, GX);
    }
}